// Round 3
// baseline (230.940 us; speedup 1.0000x reference)
//
#include <hip/hip_runtime.h>
#include <cmath>

// DBRX router, fused single kernel.
// logits = x[16384,6144] @ W[6144,16]; softmax; top-4; L1-normalize.
// Outputs flat: weights fp32[16384*16] | top_weights fp32[16384*4] | experts(as float)[16384*4]
//
// Structure: block = 8 waves, 64 tokens (lane = token). Wave wv owns d-slice
// [wv*768, (wv+1)*768). x staged coalesced -> LDS transpose (regs, depth-2
// prefetch, no in-loop barriers; per-wave private LDS region). W read at
// wave-uniform addresses -> compiler scalarizes to s_load (SGPR operand in
// v_fma: zero LDS/VGPR cost for W). Cross-wave reduce + softmax/top-4 in
// epilogue via LDS (overlaid on the x tile, barrier-separated).

namespace {
constexpr int TOKENS = 16384;
constexpr int DIM    = 6144;
constexpr int NE     = 16;
constexpr int TOPK   = 4;
constexpr int WAVES  = 8;
constexpr int T_TILE = 64;               // tokens per block (= lanes)
constexpr int KS     = DIM / WAVES;      // 768 d per wave
constexpr int DC     = 16;               // d per pipeline chunk
constexpr int NCHUNK = KS / DC;          // 48
constexpr int XPAD   = 66;               // token-dim stride: <=2-way bank alias (free)
constexpr int BPAD   = 17;               // reduce-buffer row stride: 2-way (free)
constexpr int TOPW_OFF = TOKENS * NE;                // 262144
constexpr int EXP_OFF  = TOPW_OFF + TOKENS * TOPK;   // 327680
}

__global__ __launch_bounds__(WAVES * 64) void router_fused_kernel(
    const float* __restrict__ x, const float* __restrict__ W,
    float* __restrict__ out)
{
    // overlay: x-transpose tile (8448 floats) and reduce buffer (8704 floats)
    __shared__ float smem[WAVES * T_TILE * BPAD];    // 34.8 KB
    float (*x_lds)[DC][XPAD] = reinterpret_cast<float(*)[DC][XPAD]>(smem);
    float (*red)[T_TILE][BPAD] = reinterpret_cast<float(*)[T_TILE][BPAD]>(smem);

    const int tid  = threadIdx.x;
    const int lane = tid & 63;
    const int wv   = tid >> 6;
    const int t0   = blockIdx.x * T_TILE;
    const int d0   = wv * KS;
    const int m    = lane & 3;            // float4 slot within 16-float row chunk
    const int r0   = lane >> 2;           // token row base (0..15)

    const float* xb = x + (size_t)(t0 + r0) * DIM + d0 + m * 4;

    float acc[NE];
    #pragma unroll
    for (int e = 0; e < NE; ++e) acc[e] = 0.f;

    float4 v0[4], v1[4], v2[4];
    #pragma unroll
    for (int it = 0; it < 4; ++it)
        v0[it] = *reinterpret_cast<const float4*>(xb + (size_t)(16 * it) * DIM);
    #pragma unroll
    for (int it = 0; it < 4; ++it)
        v1[it] = *reinterpret_cast<const float4*>(xb + (size_t)(16 * it) * DIM + DC);

    for (int c = 0; c < NCHUNK; ++c) {
        // transpose-write chunk c into this wave's private LDS region
        #pragma unroll
        for (int it = 0; it < 4; ++it) {
            const int r = r0 + 16 * it;
            const int d = m * 4;
            x_lds[wv][d + 0][r] = v0[it].x;
            x_lds[wv][d + 1][r] = v0[it].y;
            x_lds[wv][d + 2][r] = v0[it].z;
            x_lds[wv][d + 3][r] = v0[it].w;
        }
        // issue chunk c+2 global loads (in flight under this chunk's compute)
        if (c + 2 < NCHUNK) {
            #pragma unroll
            for (int it = 0; it < 4; ++it)
                v2[it] = *reinterpret_cast<const float4*>(
                    xb + (size_t)(16 * it) * DIM + (size_t)(c + 2) * DC);
        }
        // compute: x from LDS (lane-consecutive, conflict-free);
        // W at wave-uniform address -> s_load to SGPRs, free operand in v_fma
        const float* wp = W + (size_t)(d0 + c * DC) * NE;
        #pragma unroll
        for (int dd = 0; dd < DC; ++dd) {
            const float xv = x_lds[wv][dd][lane];
            const float4 w0 = *reinterpret_cast<const float4*>(wp + dd * NE + 0);
            const float4 w1 = *reinterpret_cast<const float4*>(wp + dd * NE + 4);
            const float4 w2 = *reinterpret_cast<const float4*>(wp + dd * NE + 8);
            const float4 w3 = *reinterpret_cast<const float4*>(wp + dd * NE + 12);
            acc[0]  = fmaf(xv, w0.x, acc[0]);
            acc[1]  = fmaf(xv, w0.y, acc[1]);
            acc[2]  = fmaf(xv, w0.z, acc[2]);
            acc[3]  = fmaf(xv, w0.w, acc[3]);
            acc[4]  = fmaf(xv, w1.x, acc[4]);
            acc[5]  = fmaf(xv, w1.y, acc[5]);
            acc[6]  = fmaf(xv, w1.z, acc[6]);
            acc[7]  = fmaf(xv, w1.w, acc[7]);
            acc[8]  = fmaf(xv, w2.x, acc[8]);
            acc[9]  = fmaf(xv, w2.y, acc[9]);
            acc[10] = fmaf(xv, w2.z, acc[10]);
            acc[11] = fmaf(xv, w2.w, acc[11]);
            acc[12] = fmaf(xv, w3.x, acc[12]);
            acc[13] = fmaf(xv, w3.y, acc[13]);
            acc[14] = fmaf(xv, w3.z, acc[14]);
            acc[15] = fmaf(xv, w3.w, acc[15]);
        }
        #pragma unroll
        for (int it = 0; it < 4; ++it) { v0[it] = v1[it]; v1[it] = v2[it]; }
    }

    // ---- cross-wave reduce + epilogue ----
    __syncthreads();   // all waves done reading x_lds before overlay reuse
    #pragma unroll
    for (int e = 0; e < NE; ++e) red[wv][lane][e] = acc[e];
    __syncthreads();   // spills visible

    if (tid < T_TILE) {
        const int t = tid;
        float l[NE];
        #pragma unroll
        for (int e = 0; e < NE; ++e) {
            float s = red[0][t][e];
            #pragma unroll
            for (int w = 1; w < WAVES; ++w) s += red[w][t][e];
            l[e] = s;
        }
        // softmax (max-subtracted, like jax.nn.softmax)
        float mx = l[0];
        #pragma unroll
        for (int e = 1; e < NE; ++e) mx = fmaxf(mx, l[e]);
        float w[NE];
        float sum = 0.f;
        #pragma unroll
        for (int e = 0; e < NE; ++e) { w[e] = expf(l[e] - mx); sum += w[e]; }
        const float inv = 1.f / sum;
        #pragma unroll
        for (int e = 0; e < NE; ++e) w[e] *= inv;

        // stable top-4: strict '>' keeps lowest index on ties (matches jax.lax.top_k)
        int   idx[TOPK];
        float tw[TOPK];
        unsigned used = 0;
        #pragma unroll
        for (int k = 0; k < TOPK; ++k) {
            float best = -1.f;
            int   bi   = 0;
            #pragma unroll
            for (int e = 0; e < NE; ++e) {
                const bool avail = ((used >> e) & 1u) == 0u;
                if (avail && w[e] > best) { best = w[e]; bi = e; }
            }
            used |= (1u << bi);
            idx[k] = bi;
            tw[k]  = best;
        }
        const float s4 = tw[0] + tw[1] + tw[2] + tw[3];
        const float rinv = 1.f / s4;

        const int tt = t0 + t;
        float4* o0 = reinterpret_cast<float4*>(out + (size_t)tt * NE);
        o0[0] = make_float4(w[0], w[1], w[2], w[3]);
        o0[1] = make_float4(w[4], w[5], w[6], w[7]);
        o0[2] = make_float4(w[8], w[9], w[10], w[11]);
        o0[3] = make_float4(w[12], w[13], w[14], w[15]);
        *reinterpret_cast<float4*>(out + TOPW_OFF + (size_t)tt * TOPK) =
            make_float4(tw[0] * rinv, tw[1] * rinv, tw[2] * rinv, tw[3] * rinv);
        *reinterpret_cast<float4*>(out + EXP_OFF + (size_t)tt * TOPK) =
            make_float4((float)idx[0], (float)idx[1], (float)idx[2], (float)idx[3]);
    }
}

extern "C" void kernel_launch(void* const* d_in, const int* in_sizes, int n_in,
                              void* d_out, int out_size, void* d_ws, size_t ws_size,
                              hipStream_t stream) {
    const float* x = (const float*)d_in[0];
    const float* W = (const float*)d_in[1];
    float* out = (float*)d_out;
    (void)d_ws; (void)ws_size;

    router_fused_kernel<<<TOKENS / T_TILE, WAVES * 64, 0, stream>>>(x, W, out);
}